// Round 1
// baseline (19396.710 us; speedup 1.0000x reference)
//
#include <hip/hip_runtime.h>
#include <math.h>

#define BB 8
#define SS 2048
#define DD 512
#define LL 6
#define FFD 2048   // 4*D

enum { EPI_NONE = 0, EPI_BIAS = 1, EPI_RELU = 2, EPI_RES = 3, EPI_ATTN = 4 };

// ---------------- helpers ----------------
__device__ __forceinline__ void blockReduce2(float& a, float& b, float* sm) {
#pragma unroll
    for (int off = 32; off; off >>= 1) {
        a += __shfl_down(a, off);
        b += __shfl_down(b, off);
    }
    int lane = threadIdx.x & 63;
    int w = threadIdx.x >> 6;
    if (lane == 0) { sm[w] = a; sm[4 + w] = b; }
    __syncthreads();
    a = sm[0] + sm[1] + sm[2] + sm[3];
    b = sm[4] + sm[5] + sm[6] + sm[7];
    __syncthreads();
}

// ---------------- encoder: x = [z,c]@enc_w^T + enc_b + posenc ----------------
__global__ __launch_bounds__(256) void encode_kernel(
    const float* __restrict__ z, const float* __restrict__ c,
    const float* __restrict__ enc_w, const float* __restrict__ enc_b,
    float* __restrict__ x)
{
    int idx = blockIdx.x * 256 + threadIdx.x;
    int d  = idx & (DD - 1);
    int bs = idx >> 9;               // b*S + s
    int s  = bs & (SS - 1);
    float v = z[bs] * enc_w[2 * d] + c[bs] * enc_w[2 * d + 1] + enc_b[d];
    // div = exp(-(2*(d/2)) * ln(10000)/D)
    float div = expf(-(float)(d & ~1) * (9.210340371976184f / 512.0f));
    float ang = (float)s * div;
    v += (d & 1) ? cosf(ang) : sinf(ang);
    x[idx] = v;
}

// ---------------- layernorm: dst = LN(src) * w + b ----------------
__global__ __launch_bounds__(256) void ln_kernel(
    const float* __restrict__ src, const float* __restrict__ w,
    const float* __restrict__ b, float* __restrict__ dst)
{
    __shared__ float sm[8];
    size_t row = blockIdx.x;
    const float* p = src + row * DD;
    int t = threadIdx.x;
    float v0 = p[t], v1 = p[t + 256];
    float s = v0 + v1, sq = v0 * v0 + v1 * v1;
    blockReduce2(s, sq, sm);
    float mean = s * (1.0f / DD);
    float var  = sq * (1.0f / DD) - mean * mean;
    float rs   = rsqrtf(var + 1e-5f);
    dst[row * DD + t]       = (v0 - mean) * rs * w[t] + b[t];
    dst[row * DD + t + 256] = (v1 - mean) * rs * w[t + 256] + b[t + 256];
}

// -------- fused: x = LN(x + att, w1,b1); xn = LN(x, w2,b2) --------
__global__ __launch_bounds__(256) void add_ln_ln_kernel(
    float* __restrict__ x, const float* __restrict__ att,
    const float* __restrict__ w1, const float* __restrict__ b1,
    const float* __restrict__ w2, const float* __restrict__ b2,
    float* __restrict__ xn)
{
    __shared__ float sm[8];
    size_t row = blockIdx.x;
    int t = threadIdx.x;
    float v0 = x[row * DD + t] + att[row * DD + t];
    float v1 = x[row * DD + t + 256] + att[row * DD + t + 256];
    float s = v0 + v1, sq = v0 * v0 + v1 * v1;
    blockReduce2(s, sq, sm);
    float mean = s * (1.0f / DD);
    float var  = sq * (1.0f / DD) - mean * mean;
    float rs   = rsqrtf(var + 1e-5f);
    float y0 = (v0 - mean) * rs * w1[t] + b1[t];
    float y1 = (v1 - mean) * rs * w1[t + 256] + b1[t + 256];
    x[row * DD + t]       = y0;
    x[row * DD + t + 256] = y1;
    // second LN on y
    s = y0 + y1; sq = y0 * y0 + y1 * y1;
    blockReduce2(s, sq, sm);
    mean = s * (1.0f / DD);
    var  = sq * (1.0f / DD) - mean * mean;
    rs   = rsqrtf(var + 1e-5f);
    xn[row * DD + t]       = (y0 - mean) * rs * w2[t] + b2[t];
    xn[row * DD + t + 256] = (y1 - mean) * rs * w2[t + 256] + b2[t + 256];
}

// ---------------- NT GEMM: C[m,n] = sum_k A[m,k]*W[n,k] (+ epilogue) ----------------
// Tile 64x64, BK=16, 256 threads, 4x4 micro-tile per thread.
// blockIdx.z batches with element strides sA,sW,sC,sR.
// EPI_ATTN: C = acc*alpha + beta0*cos(w1*dist) + beta1*cos(w2*dist), dist=|m-n|,
//           beta read from `bias` pointer (device-resident).
// TRANS: store C^T per batch: C[((m/SS)*N + n)*SS + (m%SS)]  (for V^T)
template<int EPI, bool TRANS>
__global__ __launch_bounds__(256) void gemm_nt(
    const float* __restrict__ A, const float* __restrict__ W,
    const float* __restrict__ bias, const float* __restrict__ res,
    float* __restrict__ C, int M, int N, int K, float alpha,
    long long sA, long long sW, long long sC, long long sR)
{
    __shared__ __align__(16) float As[16][64];
    __shared__ __align__(16) float Bs[16][64];

    const int z = blockIdx.z;
    A += (size_t)z * sA; W += (size_t)z * sW; C += (size_t)z * sC;
    if (EPI == EPI_RES) res += (size_t)z * sR;

    const int tid = threadIdx.x;
    const int bm = blockIdx.x * 64, bn = blockIdx.y * 64;
    const int lr = tid >> 2;            // 0..63 row within tile
    const int lc = (tid & 3) << 2;      // 0,4,8,12 k within BK
    const int tm = (tid >> 4) << 2;     // micro-tile m
    const int tn = (tid & 15) << 2;     // micro-tile n

    const float* Ap = A + (size_t)(bm + lr) * K + lc;
    const float* Wp = W + (size_t)(bn + lr) * K + lc;

    float acc[4][4] = {};

    for (int k0 = 0; k0 < K; k0 += 16) {
        float4 a4 = *(const float4*)(Ap + k0);
        float4 w4 = *(const float4*)(Wp + k0);
        __syncthreads();
        As[lc + 0][lr] = a4.x; As[lc + 1][lr] = a4.y;
        As[lc + 2][lr] = a4.z; As[lc + 3][lr] = a4.w;
        Bs[lc + 0][lr] = w4.x; Bs[lc + 1][lr] = w4.y;
        Bs[lc + 2][lr] = w4.z; Bs[lc + 3][lr] = w4.w;
        __syncthreads();
#pragma unroll
        for (int k = 0; k < 16; ++k) {
            float4 av = *(const float4*)&As[k][tm];
            float4 bv = *(const float4*)&Bs[k][tn];
            acc[0][0] += av.x * bv.x; acc[0][1] += av.x * bv.y;
            acc[0][2] += av.x * bv.z; acc[0][3] += av.x * bv.w;
            acc[1][0] += av.y * bv.x; acc[1][1] += av.y * bv.y;
            acc[1][2] += av.y * bv.z; acc[1][3] += av.y * bv.w;
            acc[2][0] += av.z * bv.x; acc[2][1] += av.z * bv.y;
            acc[2][2] += av.z * bv.z; acc[2][3] += av.z * bv.w;
            acc[3][0] += av.w * bv.x; acc[3][1] += av.w * bv.y;
            acc[3][2] += av.w * bv.z; acc[3][3] += av.w * bv.w;
        }
    }

    float beta0 = 0.f, beta1 = 0.f;
    if (EPI == EPI_ATTN) { beta0 = bias[0]; beta1 = bias[1]; }

#pragma unroll
    for (int i = 0; i < 4; ++i) {
        const int m = bm + tm + i;
#pragma unroll
        for (int j = 0; j < 4; ++j) {
            const int n = bn + tn + j;
            float v = acc[i][j];
            if (EPI == EPI_ATTN) {
                float dist = fabsf((float)(m - n));
                v = v * alpha + beta0 * cosf(0.26179938779914944f * dist)
                              + beta1 * cosf(0.008726646259971648f * dist);
            } else {
                if (EPI != EPI_NONE) v += bias[n];
                if (EPI == EPI_RELU) v = fmaxf(v, 0.0f);
                if (EPI == EPI_RES)  v += res[(size_t)m * N + n];
            }
            if (TRANS) {
                int b = m >> 11;            // m / SS
                int s = m & (SS - 1);       // m % SS
                C[((size_t)b * N + n) * SS + s] = v;
            } else {
                C[(size_t)m * N + n] = v;
            }
        }
    }
}

// ---------------- softmax over rows of [rows, SS] ----------------
__global__ __launch_bounds__(256) void softmax_kernel(float* __restrict__ p)
{
    __shared__ float sm[8];
    size_t row = blockIdx.x;
    float* r = p + row * SS;
    int t = threadIdx.x;
    float vals[8];
    float mx = -1e30f;
#pragma unroll
    for (int i = 0; i < 8; ++i) { vals[i] = r[t + 256 * i]; mx = fmaxf(mx, vals[i]); }
#pragma unroll
    for (int off = 32; off; off >>= 1) mx = fmaxf(mx, __shfl_down(mx, off));
    int lane = t & 63, w = t >> 6;
    if (lane == 0) sm[w] = mx;
    __syncthreads();
    mx = fmaxf(fmaxf(sm[0], sm[1]), fmaxf(sm[2], sm[3]));
    __syncthreads();
    float s = 0.f;
#pragma unroll
    for (int i = 0; i < 8; ++i) { vals[i] = __expf(vals[i] - mx); s += vals[i]; }
#pragma unroll
    for (int off = 32; off; off >>= 1) s += __shfl_down(s, off);
    if (lane == 0) sm[w] = s;
    __syncthreads();
    s = sm[0] + sm[1] + sm[2] + sm[3];
    float inv = 1.0f / s;
#pragma unroll
    for (int i = 0; i < 8; ++i) r[t + 256 * i] = vals[i] * inv;
}

// ---------------- out = x @ out_w^T + out_b  (ODIM=1) ----------------
__global__ __launch_bounds__(256) void out_kernel(
    const float* __restrict__ x, const float* __restrict__ ow,
    const float* __restrict__ ob, float* __restrict__ out)
{
    int row = blockIdx.x * 4 + (threadIdx.x >> 6);
    int lane = threadIdx.x & 63;
    const float* p = x + (size_t)row * DD;
    float s = 0.f;
#pragma unroll
    for (int k = 0; k < 8; ++k) s += p[lane + 64 * k] * ow[lane + 64 * k];
#pragma unroll
    for (int off = 32; off; off >>= 1) s += __shfl_down(s, off);
    if (lane == 0) out[row] = s + ob[0];
}

// ---------------- launch ----------------
extern "C" void kernel_launch(void* const* d_in, const int* in_sizes, int n_in,
                              void* d_out, int out_size, void* d_ws, size_t ws_size,
                              hipStream_t stream)
{
    (void)in_sizes; (void)n_in; (void)out_size;
    const float* z     = (const float*)d_in[0];
    const float* c     = (const float*)d_in[1];
    const float* enc_w = (const float*)d_in[2];
    const float* enc_b = (const float*)d_in[3];
    const float* beta  = (const float*)d_in[4];
    const float* wq    = (const float*)d_in[5];
    const float* bq    = (const float*)d_in[6];
    const float* wk    = (const float*)d_in[7];
    const float* bk    = (const float*)d_in[8];
    const float* wv    = (const float*)d_in[9];
    const float* bv    = (const float*)d_in[10];
    const float* ln1w  = (const float*)d_in[11];
    const float* ln1b  = (const float*)d_in[12];
    const float* ln2w  = (const float*)d_in[13];
    const float* ln2b  = (const float*)d_in[14];
    const float* ff1w  = (const float*)d_in[15];
    const float* ff1b  = (const float*)d_in[16];
    const float* ff2w  = (const float*)d_in[17];
    const float* ff2b  = (const float*)d_in[18];
    const float* ow    = (const float*)d_in[19];
    const float* ob    = (const float*)d_in[20];

    const size_t BSD = (size_t)BB * SS * DD;      // 8.39M floats
    float* ws = (float*)d_ws;
    float* x  = ws;  ws += BSD;
    float* xn = ws;  ws += BSD;
    float* q  = ws;  ws += BSD;                   // later reused for att_out
    float* kk = ws;  ws += BSD;
    float* vt = ws;  ws += BSD;                   // V^T, layout [B][D][S]

    // big path: full-batch probs [B,S,S] + h [B,S,4D]  => 436 MB total
    const size_t needBig = (5 * BSD + (size_t)BB * SS * SS + (size_t)BB * SS * FFD) * 4;
    const bool big = ws_size >= needBig;
    float* pr = ws;  ws += big ? (size_t)BB * SS * SS : (size_t)SS * SS;
    float* h  = ws;

    const float alpha = 0.04419417382415922f;     // 1/sqrt(512)
    const int BS = BB * SS;

    encode_kernel<<<dim3(BS * DD / 256), 256, 0, stream>>>(z, c, enc_w, enc_b, x);

    for (int l = 0; l < LL; ++l) {
        const float* wql = wq + (size_t)l * DD * DD;
        const float* wkl = wk + (size_t)l * DD * DD;
        const float* wvl = wv + (size_t)l * DD * DD;
        const float* f1w = ff1w + (size_t)l * FFD * DD;
        const float* f2w = ff2w + (size_t)l * DD * FFD;

        ln_kernel<<<BS, 256, 0, stream>>>(x, ln1w + l * DD, ln1b + l * DD, xn);

        dim3 gqkv(BS / 64, DD / 64, 1);
        gemm_nt<EPI_BIAS, false><<<gqkv, 256, 0, stream>>>(xn, wql, bq + l * DD, nullptr, q,  BS, DD, DD, 0, 0, 0, 0, 0);
        gemm_nt<EPI_BIAS, false><<<gqkv, 256, 0, stream>>>(xn, wkl, bk + l * DD, nullptr, kk, BS, DD, DD, 0, 0, 0, 0, 0);
        gemm_nt<EPI_BIAS, true ><<<gqkv, 256, 0, stream>>>(xn, wvl, bv + l * DD, nullptr, vt, BS, DD, DD, 0, 0, 0, 0, 0);

        const long long sQ = (long long)SS * DD, sP = (long long)SS * SS, sV = (long long)DD * SS;
        if (big) {
            gemm_nt<EPI_ATTN, false><<<dim3(SS / 64, SS / 64, BB), 256, 0, stream>>>(
                q, kk, beta + 2 * l, nullptr, pr, SS, SS, DD, alpha, sQ, sQ, sP, 0);
            softmax_kernel<<<BS, 256, 0, stream>>>(pr);
            gemm_nt<EPI_NONE, false><<<dim3(SS / 64, DD / 64, BB), 256, 0, stream>>>(
                pr, vt, nullptr, nullptr, q, SS, DD, SS, 0, sP, sV, sQ, 0);
        } else {
            for (int b = 0; b < BB; ++b) {
                gemm_nt<EPI_ATTN, false><<<dim3(SS / 64, SS / 64, 1), 256, 0, stream>>>(
                    q + b * sQ, kk + b * sQ, beta + 2 * l, nullptr, pr, SS, SS, DD, alpha, 0, 0, 0, 0);
                softmax_kernel<<<SS, 256, 0, stream>>>(pr);
                gemm_nt<EPI_NONE, false><<<dim3(SS / 64, DD / 64, 1), 256, 0, stream>>>(
                    pr, vt + b * sV, nullptr, nullptr, q + b * sQ, SS, DD, SS, 0, 0, 0, 0, 0);
            }
        }

        add_ln_ln_kernel<<<BS, 256, 0, stream>>>(x, q, ln1w + l * DD, ln1b + l * DD,
                                                 ln2w + l * DD, ln2b + l * DD, xn);

        if (big) {
            gemm_nt<EPI_RELU, false><<<dim3(BS / 64, FFD / 64, 1), 256, 0, stream>>>(
                xn, f1w, ff1b + l * FFD, nullptr, h, BS, FFD, DD, 0, 0, 0, 0, 0);
            gemm_nt<EPI_RES, false><<<dim3(BS / 64, DD / 64, 1), 256, 0, stream>>>(
                h, f2w, ff2b + l * DD, x, x, BS, DD, FFD, 0, 0, 0, 0, 0);
        } else {
            for (int b = 0; b < BB; ++b) {
                const float* xnb = xn + (size_t)b * SS * DD;
                float* xb = x + (size_t)b * SS * DD;
                gemm_nt<EPI_RELU, false><<<dim3(SS / 64, FFD / 64, 1), 256, 0, stream>>>(
                    xnb, f1w, ff1b + l * FFD, nullptr, h, SS, FFD, DD, 0, 0, 0, 0, 0);
                gemm_nt<EPI_RES, false><<<dim3(SS / 64, DD / 64, 1), 256, 0, stream>>>(
                    h, f2w, ff2b + l * DD, xb, xb, SS, DD, FFD, 0, 0, 0, 0, 0);
            }
        }
    }

    out_kernel<<<BS / 4, 256, 0, stream>>>(x, ow, ob, (float*)d_out);
}

// Round 2
// 6893.033 us; speedup vs baseline: 2.8140x; 2.8140x over previous
//
#include <hip/hip_runtime.h>
#include <math.h>

#define BB 8
#define SS 2048
#define DD 512
#define LL 6
#define FFD 2048   // 4*D

typedef _Float16 half_t;
typedef __attribute__((ext_vector_type(8))) _Float16 half8;
typedef __attribute__((ext_vector_type(4))) _Float16 half4;
typedef __attribute__((ext_vector_type(4))) float f32x4;

enum { EPI_NONE = 0, EPI_BIAS = 1, EPI_RELU = 2, EPI_RES = 3, EPI_ATTN = 4 };

// ---------------- async global->LDS, 16B per lane ----------------
__device__ __forceinline__ void gl_lds16(const void* g, void* l) {
    __builtin_amdgcn_global_load_lds(
        (const __attribute__((address_space(1))) unsigned int*)g,
        (__attribute__((address_space(3))) unsigned int*)l,
        16, 0, 0);
}

// ---------------- helpers ----------------
__device__ __forceinline__ void blockReduce2(float& a, float& b, float* sm) {
#pragma unroll
    for (int off = 32; off; off >>= 1) {
        a += __shfl_down(a, off);
        b += __shfl_down(b, off);
    }
    int lane = threadIdx.x & 63;
    int w = threadIdx.x >> 6;
    if (lane == 0) { sm[w] = a; sm[4 + w] = b; }
    __syncthreads();
    a = sm[0] + sm[1] + sm[2] + sm[3];
    b = sm[4] + sm[5] + sm[6] + sm[7];
    __syncthreads();
}

// ---------------- encoder ----------------
__global__ __launch_bounds__(256) void encode_kernel(
    const float* __restrict__ z, const float* __restrict__ c,
    const float* __restrict__ enc_w, const float* __restrict__ enc_b,
    float* __restrict__ x)
{
    int idx = blockIdx.x * 256 + threadIdx.x;
    int d  = idx & (DD - 1);
    int bs = idx >> 9;
    int s  = bs & (SS - 1);
    float v = z[bs] * enc_w[2 * d] + c[bs] * enc_w[2 * d + 1] + enc_b[d];
    float div = expf(-(float)(d & ~1) * (9.210340371976184f / 512.0f));
    float ang = (float)s * div;
    v += (d & 1) ? cosf(ang) : sinf(ang);
    x[idx] = v;
}

// ---------------- fp32 -> fp16 conversion ----------------
__global__ __launch_bounds__(256) void f2h_kernel(
    const float* __restrict__ in, half_t* __restrict__ out, int n)
{
    int i = blockIdx.x * 256 + threadIdx.x;
    if (i < n) out[i] = (half_t)in[i];
}

// ---------------- attention bias tables: tbl[l][d] ----------------
__global__ __launch_bounds__(256) void bias_table_kernel(
    const float* __restrict__ beta, float* __restrict__ tbl)
{
    int i = blockIdx.x * 256 + threadIdx.x;   // L*2048
    int l = i >> 11, d = i & (SS - 1);
    tbl[i] = beta[2 * l] * cosf(0.2617993877991494f * d)
           + beta[2 * l + 1] * cosf(0.008726646259971648f * d);
}

// ---------------- LN: dst(half) = LN(src) * w + b ----------------
__global__ __launch_bounds__(256) void ln_kernel(
    const float* __restrict__ src, const float* __restrict__ w,
    const float* __restrict__ b, half_t* __restrict__ dst)
{
    __shared__ float sm[8];
    size_t row = blockIdx.x;
    const float* p = src + row * DD;
    int t = threadIdx.x;
    float v0 = p[t], v1 = p[t + 256];
    float s = v0 + v1, sq = v0 * v0 + v1 * v1;
    blockReduce2(s, sq, sm);
    float mean = s * (1.0f / DD);
    float var  = sq * (1.0f / DD) - mean * mean;
    float rs   = rsqrtf(var + 1e-5f);
    dst[row * DD + t]       = (half_t)((v0 - mean) * rs * w[t] + b[t]);
    dst[row * DD + t + 256] = (half_t)((v1 - mean) * rs * w[t + 256] + b[t + 256]);
}

// -------- fused: x = LN(x + att, w1,b1); xn(half) = LN(x, w2,b2) --------
__global__ __launch_bounds__(256) void add_ln_ln_kernel(
    float* __restrict__ x, const float* __restrict__ att,
    const float* __restrict__ w1, const float* __restrict__ b1,
    const float* __restrict__ w2, const float* __restrict__ b2,
    half_t* __restrict__ xn)
{
    __shared__ float sm[8];
    size_t row = blockIdx.x;
    int t = threadIdx.x;
    float v0 = x[row * DD + t] + att[row * DD + t];
    float v1 = x[row * DD + t + 256] + att[row * DD + t + 256];
    float s = v0 + v1, sq = v0 * v0 + v1 * v1;
    blockReduce2(s, sq, sm);
    float mean = s * (1.0f / DD);
    float var  = sq * (1.0f / DD) - mean * mean;
    float rs   = rsqrtf(var + 1e-5f);
    float y0 = (v0 - mean) * rs * w1[t] + b1[t];
    float y1 = (v1 - mean) * rs * w1[t + 256] + b1[t + 256];
    x[row * DD + t]       = y0;
    x[row * DD + t + 256] = y1;
    s = y0 + y1; sq = y0 * y0 + y1 * y1;
    blockReduce2(s, sq, sm);
    mean = s * (1.0f / DD);
    var  = sq * (1.0f / DD) - mean * mean;
    rs   = rsqrtf(var + 1e-5f);
    xn[row * DD + t]       = (half_t)((y0 - mean) * rs * w2[t] + b2[t]);
    xn[row * DD + t + 256] = (half_t)((y1 - mean) * rs * w2[t + 256] + b2[t + 256]);
}

// ---------------- MFMA fp16 NT GEMM ----------------
// C[m,n] = sum_k A[m,k]*W[n,k]  (both operands K-contiguous)
// 128x128 tile, BK=32, 256 threads = 4 waves (2x2 of 64x64), 4x4 MFMA 16x16x32.
// Staging via global_load_lds width=16 (LDS layout = exact lane order).
// Epilogues:
//   EPI_BIAS: +bias[n]            EPI_RELU: +bias[n], relu
//   EPI_RES : +bias[n]+res[m*N+n] EPI_ATTN: *alpha + tbl[|m-n|]  (bias=tbl)
// TRANS (for V^T): store half4 at C[(b*N+n)*SS + s], b=m>>11, s=m&2047
// OHALF: output half_t else float
template<int EPI, bool TRANS, bool OHALF>
__global__ __launch_bounds__(256) void gemm_mfma(
    const half_t* __restrict__ A, const half_t* __restrict__ W,
    const float* __restrict__ bias, const float* __restrict__ res,
    void* __restrict__ Cp, int M, int N, int K, float alpha,
    long long sA, long long sW, long long sC)
{
    __shared__ __align__(16) half_t As[128 * 32];
    __shared__ __align__(16) half_t Bs[128 * 32];

    const int z = blockIdx.z;
    A += (size_t)z * sA; W += (size_t)z * sW;
    float*  Cf = (float*)Cp  + (size_t)z * sC;
    half_t* Ch = (half_t*)Cp + (size_t)z * sC;

    const int tid = threadIdx.x;
    const int wv = tid >> 6, ln = tid & 63;
    const int bm = blockIdx.x * 128, bn = blockIdx.y * 128;
    const int wm = (wv & 1) * 64, wn = (wv >> 1) * 64;

    // staging coords: each thread stages 2x16B for A and 2x16B for B
    const int srow = wv * 16 + (ln >> 2);        // 0..63
    const int scol = (ln & 3) * 8;               // k offset in halfs
    const half_t* Ag = A + (size_t)(bm + srow) * K + scol;
    const half_t* Bg = W + (size_t)(bn + srow) * K + scol;
    char* lA = (char*)As + wv * 1024 + (ln & 63) * 0;  // base; HW adds lane*16
    char* lB = (char*)Bs + wv * 1024;
    lA = (char*)As + wv * 1024;

    f32x4 acc[4][4] = {};

    const int lane15 = ln & 15, quad = ln >> 4;
    const int koff = quad * 8;

    for (int k0 = 0; k0 < K; k0 += 32) {
        __syncthreads();   // previous iter's LDS reads done
        gl_lds16(Ag + k0,                lA);
        gl_lds16(Ag + (size_t)64 * K + k0, lA + 4096);
        gl_lds16(Bg + k0,                lB);
        gl_lds16(Bg + (size_t)64 * K + k0, lB + 4096);
        __syncthreads();   // drains vmcnt before barrier release

        half8 aF[4], bF[4];
#pragma unroll
        for (int i = 0; i < 4; ++i)
            aF[i] = *(const half8*)&As[(wm + i * 16 + lane15) * 32 + koff];
#pragma unroll
        for (int j = 0; j < 4; ++j)
            bF[j] = *(const half8*)&Bs[(wn + j * 16 + lane15) * 32 + koff];
#pragma unroll
        for (int i = 0; i < 4; ++i)
#pragma unroll
            for (int j = 0; j < 4; ++j)
                acc[i][j] = __builtin_amdgcn_mfma_f32_16x16x32_f16(
                    aF[i], bF[j], acc[i][j], 0, 0, 0);
    }

    // epilogue; C/D layout: col = lane&15, row = quad*4 + r
#pragma unroll
    for (int i = 0; i < 4; ++i) {
        const int m0 = bm + wm + i * 16 + quad * 4;
#pragma unroll
        for (int j = 0; j < 4; ++j) {
            const int gn = bn + wn + j * 16 + lane15;
            if (TRANS) {
                half4 pk;
#pragma unroll
                for (int r = 0; r < 4; ++r) {
                    float v = acc[i][j][r];
                    if (EPI != EPI_NONE && EPI != EPI_ATTN) v += bias[gn];
                    pk[r] = (half_t)v;
                }
                const int b = m0 >> 11, s0 = m0 & (SS - 1);
                *(half4*)&Ch[((size_t)b * N + gn) * SS + s0] = pk;
            } else {
#pragma unroll
                for (int r = 0; r < 4; ++r) {
                    const int gm = m0 + r;
                    float v = acc[i][j][r];
                    if (EPI == EPI_ATTN) {
                        int dist = gm - gn; if (dist < 0) dist = -dist;
                        v = v * alpha + bias[dist];
                    } else {
                        if (EPI != EPI_NONE) v += bias[gn];
                        if (EPI == EPI_RELU) v = fmaxf(v, 0.0f);
                        if (EPI == EPI_RES)  v += res[(size_t)gm * N + gn];
                    }
                    if (OHALF) Ch[(size_t)gm * N + gn] = (half_t)v;
                    else       Cf[(size_t)gm * N + gn] = v;
                }
            }
        }
    }
}

// ---------------- softmax: fp32 scores -> fp16 probs ----------------
__global__ __launch_bounds__(256) void softmax_kernel(
    const float* __restrict__ sc, half_t* __restrict__ pr)
{
    __shared__ float sm[8];
    size_t row = blockIdx.x;
    const float* r = sc + row * SS;
    half_t* o = pr + row * SS;
    int t = threadIdx.x;
    float vals[8];
    float mx = -1e30f;
#pragma unroll
    for (int i = 0; i < 8; ++i) { vals[i] = r[t + 256 * i]; mx = fmaxf(mx, vals[i]); }
#pragma unroll
    for (int off = 32; off; off >>= 1) mx = fmaxf(mx, __shfl_down(mx, off));
    int lane = t & 63, w = t >> 6;
    if (lane == 0) sm[w] = mx;
    __syncthreads();
    mx = fmaxf(fmaxf(sm[0], sm[1]), fmaxf(sm[2], sm[3]));
    __syncthreads();
    float s = 0.f;
#pragma unroll
    for (int i = 0; i < 8; ++i) { vals[i] = __expf(vals[i] - mx); s += vals[i]; }
#pragma unroll
    for (int off = 32; off; off >>= 1) s += __shfl_down(s, off);
    if (lane == 0) sm[w] = s;
    __syncthreads();
    s = sm[0] + sm[1] + sm[2] + sm[3];
    float inv = 1.0f / s;
#pragma unroll
    for (int i = 0; i < 8; ++i) o[t + 256 * i] = (half_t)(vals[i] * inv);
}

// ---------------- out = x @ out_w^T + out_b  (ODIM=1) ----------------
__global__ __launch_bounds__(256) void out_kernel(
    const float* __restrict__ x, const float* __restrict__ ow,
    const float* __restrict__ ob, float* __restrict__ out)
{
    int row = blockIdx.x * 4 + (threadIdx.x >> 6);
    int lane = threadIdx.x & 63;
    const float* p = x + (size_t)row * DD;
    float s = 0.f;
#pragma unroll
    for (int k = 0; k < 8; ++k) s += p[lane + 64 * k] * ow[lane + 64 * k];
#pragma unroll
    for (int off = 32; off; off >>= 1) s += __shfl_down(s, off);
    if (lane == 0) out[row] = s + ob[0];
}

// ---------------- launch ----------------
extern "C" void kernel_launch(void* const* d_in, const int* in_sizes, int n_in,
                              void* d_out, int out_size, void* d_ws, size_t ws_size,
                              hipStream_t stream)
{
    (void)in_sizes; (void)n_in; (void)out_size;
    const float* z     = (const float*)d_in[0];
    const float* c     = (const float*)d_in[1];
    const float* enc_w = (const float*)d_in[2];
    const float* enc_b = (const float*)d_in[3];
    const float* beta  = (const float*)d_in[4];
    const float* wq    = (const float*)d_in[5];
    const float* bq    = (const float*)d_in[6];
    const float* wk    = (const float*)d_in[7];
    const float* bk    = (const float*)d_in[8];
    const float* wv    = (const float*)d_in[9];
    const float* bv    = (const float*)d_in[10];
    const float* ln1w  = (const float*)d_in[11];
    const float* ln1b  = (const float*)d_in[12];
    const float* ln2w  = (const float*)d_in[13];
    const float* ln2b  = (const float*)d_in[14];
    const float* ff1w  = (const float*)d_in[15];
    const float* ff1b  = (const float*)d_in[16];
    const float* ff2w  = (const float*)d_in[17];
    const float* ff2b  = (const float*)d_in[18];
    const float* ow    = (const float*)d_in[19];
    const float* ob    = (const float*)d_in[20];

    const size_t BSD = (size_t)BB * SS * DD;       // 8.39M
    const size_t BSS = (size_t)BB * SS * SS;       // 33.6M
    const size_t SSS = (size_t)SS * SS;            // 4.19M
    const size_t SF  = (size_t)SS * FFD;           // 4.19M
    const size_t NW3 = (size_t)LL * DD * DD;       // 1.57M  (per q/k/v)
    const size_t NWF = (size_t)LL * FFD * DD;      // 6.29M  (per ff1/ff2)

    // big path needs fp32: 2*BSD + BSS + L*2048 ; fp16: 4*BSD + 2*BSS + 3*NW3 + 2*NWF
    const size_t needBig = 4 * (2 * BSD + BSS + LL * SS)
                         + 2 * (4 * BSD + 2 * BSS + 3 * NW3 + 2 * NWF);
    const bool big = ws_size >= needBig;

    char* p = (char*)d_ws;
    float* x      = (float*)p; p += BSD * 4;
    float* attout = (float*)p; p += BSD * 4;
    float* scores = (float*)p; p += (big ? BSS : SSS) * 4;
    float* tbl    = (float*)p; p += (size_t)LL * SS * 4;
    half_t* xnh   = (half_t*)p; p += BSD * 2;
    half_t* qh    = (half_t*)p; p += BSD * 2;
    half_t* kh    = (half_t*)p; p += BSD * 2;
    half_t* vth   = (half_t*)p; p += BSD * 2;   // [B][D][S]
    half_t* prh   = (half_t*)p; p += (big ? BSS : SSS) * 2;
    half_t* hh    = (half_t*)p; p += (big ? BSS : SF) * 2;
    half_t* wqh   = (half_t*)p; p += NW3 * 2;
    half_t* wkh   = (half_t*)p; p += NW3 * 2;
    half_t* wvh   = (half_t*)p; p += NW3 * 2;
    half_t* f1h   = (half_t*)p; p += NWF * 2;
    half_t* f2h   = (half_t*)p; p += NWF * 2;

    const float alpha = 0.044194173824159216f;    // 1/sqrt(512)
    const int BS = BB * SS;

    // one-time-per-call prep (weights restored from pristine every call)
    f2h_kernel<<<(int)(NW3 / 256), 256, 0, stream>>>(wq, wqh, (int)NW3);
    f2h_kernel<<<(int)(NW3 / 256), 256, 0, stream>>>(wk, wkh, (int)NW3);
    f2h_kernel<<<(int)(NW3 / 256), 256, 0, stream>>>(wv, wvh, (int)NW3);
    f2h_kernel<<<(int)(NWF / 256), 256, 0, stream>>>(ff1w, f1h, (int)NWF);
    f2h_kernel<<<(int)(NWF / 256), 256, 0, stream>>>(ff2w, f2h, (int)NWF);
    bias_table_kernel<<<LL * SS / 256, 256, 0, stream>>>(beta, tbl);

    encode_kernel<<<BS * DD / 256, 256, 0, stream>>>(z, c, enc_w, enc_b, x);

    const long long sQ = (long long)SS * DD, sP = (long long)SS * SS,
                    sV = (long long)DD * SS;

    for (int l = 0; l < LL; ++l) {
        ln_kernel<<<BS, 256, 0, stream>>>(x, ln1w + l * DD, ln1b + l * DD, xnh);

        dim3 gqkv(BS / 128, DD / 128, 1);
        gemm_mfma<EPI_BIAS, false, true><<<gqkv, 256, 0, stream>>>(
            xnh, wqh + (size_t)l * DD * DD, bq + l * DD, nullptr, qh, BS, DD, DD, 0, 0, 0, 0);
        gemm_mfma<EPI_BIAS, false, true><<<gqkv, 256, 0, stream>>>(
            xnh, wkh + (size_t)l * DD * DD, bk + l * DD, nullptr, kh, BS, DD, DD, 0, 0, 0, 0);
        gemm_mfma<EPI_BIAS, true, true><<<gqkv, 256, 0, stream>>>(
            xnh, wvh + (size_t)l * DD * DD, bv + l * DD, nullptr, vth, BS, DD, DD, 0, 0, 0, 0);

        if (big) {
            gemm_mfma<EPI_ATTN, false, false><<<dim3(SS / 128, SS / 128, BB), 256, 0, stream>>>(
                qh, kh, tbl + l * SS, nullptr, scores, SS, SS, DD, alpha, sQ, sQ, sP);
            softmax_kernel<<<BS, 256, 0, stream>>>(scores, prh);
            gemm_mfma<EPI_NONE, false, false><<<dim3(SS / 128, DD / 128, BB), 256, 0, stream>>>(
                prh, vth, nullptr, nullptr, attout, SS, DD, SS, 0, sP, sV, sQ);
        } else {
            for (int b = 0; b < BB; ++b) {
                gemm_mfma<EPI_ATTN, false, false><<<dim3(SS / 128, SS / 128, 1), 256, 0, stream>>>(
                    qh + b * sQ, kh + b * sQ, tbl + l * SS, nullptr, scores, SS, SS, DD, alpha, 0, 0, 0);
                softmax_kernel<<<SS, 256, 0, stream>>>(scores, prh);
                gemm_mfma<EPI_NONE, false, false><<<dim3(SS / 128, DD / 128, 1), 256, 0, stream>>>(
                    prh, vth + b * sV, nullptr, nullptr, attout + b * sQ, SS, DD, SS, 0, 0, 0, 0);
            }
        }

        add_ln_ln_kernel<<<BS, 256, 0, stream>>>(x, attout, ln1w + l * DD, ln1b + l * DD,
                                                 ln2w + l * DD, ln2b + l * DD, xnh);

        if (big) {
            gemm_mfma<EPI_RELU, false, true><<<dim3(BS / 128, FFD / 128, 1), 256, 0, stream>>>(
                xnh, f1h + (size_t)l * FFD * DD, ff1b + l * FFD, nullptr, hh, BS, FFD, DD, 0, 0, 0, 0);
            gemm_mfma<EPI_RES, false, false><<<dim3(BS / 128, DD / 128, 1), 256, 0, stream>>>(
                hh, f2h + (size_t)l * DD * FFD, ff2b + l * DD, x, x, BS, DD, FFD, 0, 0, 0, 0);
        } else {
            for (int b = 0; b < BB; ++b) {
                half_t* xnb = xnh + (size_t)b * SS * DD;
                float* xb = x + (size_t)b * SS * DD;
                gemm_mfma<EPI_RELU, false, true><<<dim3(SS / 128, FFD / 128, 1), 256, 0, stream>>>(
                    xnb, f1h + (size_t)l * FFD * DD, ff1b + l * FFD, nullptr, hh, SS, FFD, DD, 0, 0, 0, 0);
                gemm_mfma<EPI_RES, false, false><<<dim3(SS / 128, DD / 128, 1), 256, 0, stream>>>(
                    hh, f2h + (size_t)l * DD * FFD, ff2b + l * DD, xb, xb, SS, DD, FFD, 0, 0, 0, 0);
            }
        }
    }

    out_kernel<<<BS / 4, 256, 0, stream>>>(x, ow, ob, (float*)d_out);
}

// Round 3
// 2251.368 us; speedup vs baseline: 8.6155x; 3.0617x over previous
//
#include <hip/hip_runtime.h>
#include <math.h>

#define BB 8
#define SS 2048
#define DD 512
#define LL 6
#define FFD 2048   // 4*D

typedef _Float16 half_t;
typedef __attribute__((ext_vector_type(8))) _Float16 half8;
typedef __attribute__((ext_vector_type(4))) _Float16 half4;
typedef __attribute__((ext_vector_type(4))) float f32x4;

enum { EPI_NONE = 0, EPI_RELU = 2, EPI_RES = 3, EPI_ATTN = 4, EPI_QKV = 5 };

// ---------------- async global->LDS, 16B per lane ----------------
__device__ __forceinline__ void gl_lds16(const void* g, void* l) {
    __builtin_amdgcn_global_load_lds(
        (const __attribute__((address_space(1))) unsigned int*)g,
        (__attribute__((address_space(3))) unsigned int*)l,
        16, 0, 0);
}

__device__ __forceinline__ void blockReduce2(float& a, float& b, float* sm) {
#pragma unroll
    for (int off = 32; off; off >>= 1) {
        a += __shfl_down(a, off);
        b += __shfl_down(b, off);
    }
    int lane = threadIdx.x & 63;
    int w = threadIdx.x >> 6;
    if (lane == 0) { sm[w] = a; sm[4 + w] = b; }
    __syncthreads();
    a = sm[0] + sm[1] + sm[2] + sm[3];
    b = sm[4] + sm[5] + sm[6] + sm[7];
    __syncthreads();
}

// ---------------- encoder ----------------
__global__ __launch_bounds__(256) void encode_kernel(
    const float* __restrict__ z, const float* __restrict__ c,
    const float* __restrict__ enc_w, const float* __restrict__ enc_b,
    float* __restrict__ x)
{
    int idx = blockIdx.x * 256 + threadIdx.x;
    int d  = idx & (DD - 1);
    int bs = idx >> 9;
    int s  = bs & (SS - 1);
    float v = z[bs] * enc_w[2 * d] + c[bs] * enc_w[2 * d + 1] + enc_b[d];
    float div = expf(-(float)(d & ~1) * (9.210340371976184f / 512.0f));
    float ang = (float)s * div;
    v += (d & 1) ? cosf(ang) : sinf(ang);
    x[idx] = v;
}

// ---------------- fp32 -> fp16 ----------------
__global__ __launch_bounds__(256) void f2h_kernel(
    const float* __restrict__ in, half_t* __restrict__ out, int n)
{
    int i = blockIdx.x * 256 + threadIdx.x;
    if (i < n) out[i] = (half_t)in[i];
}

// packed [wq | wk | wv] for one layer
__global__ __launch_bounds__(256) void f2h3_kernel(
    const float* __restrict__ a, const float* __restrict__ b,
    const float* __restrict__ c, half_t* __restrict__ out)
{
    int i = blockIdx.x * 256 + threadIdx.x;          // 3*DD*DD
    int which = i >> 18;                             // /(DD*DD)=262144
    int j = i & (DD * DD - 1);
    const float* src = (which == 0) ? a : (which == 1) ? b : c;
    out[i] = (half_t)src[j];
}

// ---------------- attention bias tables: tbl[l][dist] ----------------
__global__ __launch_bounds__(256) void bias_table_kernel(
    const float* __restrict__ beta, float* __restrict__ tbl)
{
    int i = blockIdx.x * 256 + threadIdx.x;   // L*2048
    int l = i >> 11, d = i & (SS - 1);
    tbl[i] = beta[2 * l] * cosf(0.2617993877991494f * d)
           + beta[2 * l + 1] * cosf(0.008726646259971648f * d);
}

// ---------------- LN: dst(half) = LN(src)*w + b ----------------
__global__ __launch_bounds__(256) void ln_kernel(
    const float* __restrict__ src, const float* __restrict__ w,
    const float* __restrict__ b, half_t* __restrict__ dst)
{
    __shared__ float sm[8];
    size_t row = blockIdx.x;
    const float* p = src + row * DD;
    int t = threadIdx.x;
    float v0 = p[t], v1 = p[t + 256];
    float s = v0 + v1, sq = v0 * v0 + v1 * v1;
    blockReduce2(s, sq, sm);
    float mean = s * (1.0f / DD);
    float var  = sq * (1.0f / DD) - mean * mean;
    float rs   = rsqrtf(var + 1e-5f);
    dst[row * DD + t]       = (half_t)((v0 - mean) * rs * w[t] + b[t]);
    dst[row * DD + t + 256] = (half_t)((v1 - mean) * rs * w[t + 256] + b[t + 256]);
}

// -------- fused: x = LN(x + att, w1,b1); xn(half) = LN(x, w2,b2) --------
__global__ __launch_bounds__(256) void add_ln_ln_kernel(
    float* __restrict__ x, const half_t* __restrict__ att,
    const float* __restrict__ w1, const float* __restrict__ b1,
    const float* __restrict__ w2, const float* __restrict__ b2,
    half_t* __restrict__ xn)
{
    __shared__ float sm[8];
    size_t row = blockIdx.x;
    int t = threadIdx.x;
    float v0 = x[row * DD + t] + (float)att[row * DD + t];
    float v1 = x[row * DD + t + 256] + (float)att[row * DD + t + 256];
    float s = v0 + v1, sq = v0 * v0 + v1 * v1;
    blockReduce2(s, sq, sm);
    float mean = s * (1.0f / DD);
    float var  = sq * (1.0f / DD) - mean * mean;
    float rs   = rsqrtf(var + 1e-5f);
    float y0 = (v0 - mean) * rs * w1[t] + b1[t];
    float y1 = (v1 - mean) * rs * w1[t + 256] + b1[t + 256];
    x[row * DD + t]       = y0;
    x[row * DD + t + 256] = y1;
    s = y0 + y1; sq = y0 * y0 + y1 * y1;
    blockReduce2(s, sq, sm);
    mean = s * (1.0f / DD);
    var  = sq * (1.0f / DD) - mean * mean;
    rs   = rsqrtf(var + 1e-5f);
    xn[row * DD + t]       = (half_t)((y0 - mean) * rs * w2[t] + b2[t]);
    xn[row * DD + t + 256] = (half_t)((y1 - mean) * rs * w2[t + 256] + b2[t + 256]);
}

// ---------------- MFMA fp16 NT GEMM ----------------
// C[m,n] = sum_k A[m,k]*W[n,k]. Tile MT x 128, BK=32, 256 thr = 4 waves.
// MT=128: waves 2x2 of 64x64 (4x4 mfma); MT=64: waves 2x2 of 32x64 (2x4 mfma).
// EPI_QKV: N-segments of 512 -> Q (Cp,+bias), K (Ck,+biasK), V^T (Cv,+biasV,
//          stored [b][d][s]). EPI_ATTN: v*alpha + tbl[|m-n|], store half.
template<int MT, int EPI, bool OHALF>
__global__ __launch_bounds__(256) void gemm_mfma(
    const half_t* __restrict__ A, const half_t* __restrict__ W,
    const float* __restrict__ bias, const float* __restrict__ res,
    void* __restrict__ Cp, int N, int K, float alpha,
    long long sA, long long sW, long long sC,
    const float* __restrict__ biasK, const float* __restrict__ biasV,
    half_t* __restrict__ Ck, half_t* __restrict__ Cv)
{
    constexpr int TM = MT / 32;                  // mfma m-tiles per wave
    __shared__ __align__(16) half_t As[MT * 32];
    __shared__ __align__(16) half_t Bs[128 * 32];

    const int z = blockIdx.z;
    A += (size_t)z * sA; W += (size_t)z * sW;
    float*  Cf = (float*)Cp  + (size_t)z * sC;
    half_t* Ch = (half_t*)Cp + (size_t)z * sC;

    const int tid = threadIdx.x;
    const int wv = tid >> 6, ln = tid & 63;
    const int bm = blockIdx.x * MT, bn = blockIdx.y * 128;
    const int wm = (wv & 1) * (MT / 2), wn = (wv >> 1) * 64;

    const int srow = wv * 16 + (ln >> 2);        // 0..63
    const int scol = (ln & 3) * 8;
    const half_t* Ag = A + (size_t)(bm + srow) * K + scol;
    const half_t* Bg = W + (size_t)(bn + srow) * K + scol;
    char* lA = (char*)As + wv * 1024;
    char* lB = (char*)Bs + wv * 1024;

    f32x4 acc[TM][4] = {};
    const int lane15 = ln & 15, quad = ln >> 4;
    const int koff = quad * 8;

    for (int k0 = 0; k0 < K; k0 += 32) {
        __syncthreads();
        gl_lds16(Ag + k0, lA);
        if (MT == 128) gl_lds16(Ag + (size_t)64 * K + k0, lA + 4096);
        gl_lds16(Bg + k0, lB);
        gl_lds16(Bg + (size_t)64 * K + k0, lB + 4096);
        __syncthreads();

        half8 aF[TM], bF[4];
#pragma unroll
        for (int i = 0; i < TM; ++i)
            aF[i] = *(const half8*)&As[(wm + i * 16 + lane15) * 32 + koff];
#pragma unroll
        for (int j = 0; j < 4; ++j)
            bF[j] = *(const half8*)&Bs[(wn + j * 16 + lane15) * 32 + koff];
#pragma unroll
        for (int i = 0; i < TM; ++i)
#pragma unroll
            for (int j = 0; j < 4; ++j)
                acc[i][j] = __builtin_amdgcn_mfma_f32_16x16x32_f16(
                    aF[i], bF[j], acc[i][j], 0, 0, 0);
    }

    // C/D layout: col = lane&15, row = quad*4 + r
#pragma unroll
    for (int i = 0; i < TM; ++i) {
        const int m0 = bm + wm + i * 16 + quad * 4;
#pragma unroll
        for (int j = 0; j < 4; ++j) {
            const int gn = bn + wn + j * 16 + lane15;
            if (EPI == EPI_QKV) {
                const int seg = gn >> 9, nn = gn & (DD - 1);
                if (seg == 2) {                  // V^T store, packed over rows
                    half4 pk;
#pragma unroll
                    for (int r = 0; r < 4; ++r)
                        pk[r] = (half_t)(acc[i][j][r] + biasV[nn]);
                    const int b = m0 >> 11, s0 = m0 & (SS - 1);
                    *(half4*)&Cv[((size_t)b * DD + nn) * SS + s0] = pk;
                } else {
                    const float bs = (seg == 0) ? bias[nn] : biasK[nn];
                    half_t* dst = (seg == 0) ? Ch : Ck;
#pragma unroll
                    for (int r = 0; r < 4; ++r)
                        dst[(size_t)(m0 + r) * DD + nn] = (half_t)(acc[i][j][r] + bs);
                }
            } else {
#pragma unroll
                for (int r = 0; r < 4; ++r) {
                    const int gm = m0 + r;
                    float v = acc[i][j][r];
                    if (EPI == EPI_ATTN) {
                        int dist = gm - gn; if (dist < 0) dist = -dist;
                        v = v * alpha + bias[dist];
                    } else {
                        if (EPI == EPI_RELU) v = fmaxf(v + bias[gn], 0.0f);
                        if (EPI == EPI_RES)  v += bias[gn] + res[(size_t)gm * N + gn];
                    }
                    if (OHALF) Ch[(size_t)gm * N + gn] = (half_t)v;
                    else       Cf[(size_t)gm * N + gn] = v;
                }
            }
        }
    }
}

// ---------------- in-place fp16 softmax over rows of [rows, SS] ----------------
__global__ __launch_bounds__(256) void softmax_kernel(half_t* __restrict__ p)
{
    __shared__ float sm[4];
    size_t row = blockIdx.x;
    half_t* r = p + row * SS;
    int t = threadIdx.x;
    half8 v8 = ((half8*)r)[t];
    float vals[8];
    float mx = -1e30f;
#pragma unroll
    for (int i = 0; i < 8; ++i) { vals[i] = (float)v8[i]; mx = fmaxf(mx, vals[i]); }
#pragma unroll
    for (int off = 32; off; off >>= 1) mx = fmaxf(mx, __shfl_down(mx, off));
    int lane = t & 63, w = t >> 6;
    if (lane == 0) sm[w] = mx;
    __syncthreads();
    mx = fmaxf(fmaxf(sm[0], sm[1]), fmaxf(sm[2], sm[3]));
    __syncthreads();
    float s = 0.f;
#pragma unroll
    for (int i = 0; i < 8; ++i) { vals[i] = __expf(vals[i] - mx); s += vals[i]; }
#pragma unroll
    for (int off = 32; off; off >>= 1) s += __shfl_down(s, off);
    if (lane == 0) sm[w] = s;
    __syncthreads();
    s = sm[0] + sm[1] + sm[2] + sm[3];
    float inv = 1.0f / s;
#pragma unroll
    for (int i = 0; i < 8; ++i) v8[i] = (half_t)(vals[i] * inv);
    ((half8*)r)[t] = v8;
}

// ---------------- out = x @ out_w^T + out_b  (ODIM=1) ----------------
__global__ __launch_bounds__(256) void out_kernel(
    const float* __restrict__ x, const float* __restrict__ ow,
    const float* __restrict__ ob, float* __restrict__ out)
{
    int row = blockIdx.x * 4 + (threadIdx.x >> 6);
    int lane = threadIdx.x & 63;
    const float* p = x + (size_t)row * DD;
    float s = 0.f;
#pragma unroll
    for (int k = 0; k < 8; ++k) s += p[lane + 64 * k] * ow[lane + 64 * k];
#pragma unroll
    for (int off = 32; off; off >>= 1) s += __shfl_down(s, off);
    if (lane == 0) out[row] = s + ob[0];
}

// ---------------- launch ----------------
extern "C" void kernel_launch(void* const* d_in, const int* in_sizes, int n_in,
                              void* d_out, int out_size, void* d_ws, size_t ws_size,
                              hipStream_t stream)
{
    (void)in_sizes; (void)n_in; (void)out_size; (void)ws_size;
    const float* z     = (const float*)d_in[0];
    const float* c     = (const float*)d_in[1];
    const float* enc_w = (const float*)d_in[2];
    const float* enc_b = (const float*)d_in[3];
    const float* beta  = (const float*)d_in[4];
    const float* wq    = (const float*)d_in[5];
    const float* bq    = (const float*)d_in[6];
    const float* wk    = (const float*)d_in[7];
    const float* bk    = (const float*)d_in[8];
    const float* wv    = (const float*)d_in[9];
    const float* bv    = (const float*)d_in[10];
    const float* ln1w  = (const float*)d_in[11];
    const float* ln1b  = (const float*)d_in[12];
    const float* ln2w  = (const float*)d_in[13];
    const float* ln2b  = (const float*)d_in[14];
    const float* ff1w  = (const float*)d_in[15];
    const float* ff1b  = (const float*)d_in[16];
    const float* ff2w  = (const float*)d_in[17];
    const float* ff2b  = (const float*)d_in[18];
    const float* ow    = (const float*)d_in[19];
    const float* ob    = (const float*)d_in[20];

    const size_t BSD = (size_t)BB * SS * DD;   // 8.39M
    const size_t BSS = (size_t)BB * SS * SS;   // 33.6M

    // Workspace: 190.4 MB total (fits the >=202 MB proven in R1/R2).
    char* p = (char*)d_ws;
    float*  x    = (float*)p;  p += BSD * 4;        // 33.55 MB
    half_t* xnh  = (half_t*)p; p += BSD * 2;        // 16.78 MB
    half_t* sch  = (half_t*)p; p += BSS * 2;        // 67.11 MB  scores/probs in-place
    char*   pool = p;          p += BSD * 2 * 4;    // 67.11 MB
    half_t* atth = (half_t*)pool;                   // dead before hh written
    half_t* qh   = (half_t*)(pool + BSD * 2);
    half_t* kh   = (half_t*)(pool + BSD * 4);
    half_t* vth  = (half_t*)(pool + BSD * 6);       // [B][D][S]
    half_t* hh   = (half_t*)pool;                   // aliases pool (BS x FFD)
    half_t* wqkv = (half_t*)p; p += (size_t)3 * DD * DD * 2;   // 1.57 MB
    half_t* f1h  = (half_t*)p; p += (size_t)FFD * DD * 2;      // 2.10 MB
    half_t* f2h  = (half_t*)p; p += (size_t)FFD * DD * 2;      // 2.10 MB
    float*  tbl  = (float*)p;                                  // 48 KB

    const float alpha = 0.044194173824159216f;      // 1/sqrt(512)
    const int BS = BB * SS;
    const long long sQ = (long long)SS * DD, sP = (long long)SS * SS,
                    sV = (long long)DD * SS;

    bias_table_kernel<<<LL * SS / 256, 256, 0, stream>>>(beta, tbl);
    encode_kernel<<<BS * DD / 256, 256, 0, stream>>>(z, c, enc_w, enc_b, x);

    for (int l = 0; l < LL; ++l) {
        // per-layer weight conversion into the rotating fp16 buffer
        f2h3_kernel<<<3 * DD * DD / 256, 256, 0, stream>>>(
            wq + (size_t)l * DD * DD, wk + (size_t)l * DD * DD,
            wv + (size_t)l * DD * DD, wqkv);
        f2h_kernel<<<FFD * DD / 256, 256, 0, stream>>>(
            ff1w + (size_t)l * FFD * DD, f1h, FFD * DD);
        f2h_kernel<<<FFD * DD / 256, 256, 0, stream>>>(
            ff2w + (size_t)l * DD * FFD, f2h, FFD * DD);

        ln_kernel<<<BS, 256, 0, stream>>>(x, ln1w + l * DD, ln1b + l * DD, xnh);

        // fused QKV: one dispatch, 1536 blocks
        gemm_mfma<128, EPI_QKV, true><<<dim3(BS / 128, 12, 1), 256, 0, stream>>>(
            xnh, wqkv, bq + l * DD, nullptr, qh, DD, DD, 0, 0, 0, 0,
            bk + l * DD, bv + l * DD, kh, vth);

        // QK^T * alpha + cos-bias -> fp16 scores (full batch, 2048 blocks)
        gemm_mfma<128, EPI_ATTN, true><<<dim3(SS / 128, SS / 128, BB), 256, 0, stream>>>(
            qh, kh, tbl + l * SS, nullptr, sch, SS, DD, alpha, sQ, sQ, sP,
            nullptr, nullptr, nullptr, nullptr);

        softmax_kernel<<<BS, 256, 0, stream>>>(sch);

        // P @ V (64-row tiles -> 1024 blocks)
        gemm_mfma<64, EPI_NONE, true><<<dim3(SS / 64, DD / 128, BB), 256, 0, stream>>>(
            sch, vth, nullptr, nullptr, atth, DD, SS, 0, sP, sV, sQ,
            nullptr, nullptr, nullptr, nullptr);

        add_ln_ln_kernel<<<BS, 256, 0, stream>>>(x, atth, ln1w + l * DD, ln1b + l * DD,
                                                 ln2w + l * DD, ln2b + l * DD, xnh);

        // FFN
        gemm_mfma<128, EPI_RELU, true><<<dim3(BS / 128, FFD / 128, 1), 256, 0, stream>>>(
            xnh, f1h, ff1b + l * FFD, nullptr, hh, FFD, DD, 0, 0, 0, 0,
            nullptr, nullptr, nullptr, nullptr);
        gemm_mfma<64, EPI_RES, false><<<dim3(BS / 64, DD / 128, 1), 256, 0, stream>>>(
            hh, f2h, ff2b + l * DD, x, x, DD, FFD, 0, 0, 0, 0,
            nullptr, nullptr, nullptr, nullptr);
    }

    out_kernel<<<BS / 4, 256, 0, stream>>>(x, ow, ob, (float*)d_out);
}